// Round 1
// baseline (186.696 us; speedup 1.0000x reference)
//
#include <hip/hip_runtime.h>
#include <math.h>

// SpectralConv2d via partial separable DFT (only 32x16 modes of rfft2 used).
// B=16, CIN=COUT=32, H=W=256, M1=M2=16.
#define BB 16
#define CIN 32
#define COUT 32
#define HH 256
#define WW 256
#define M1 16
#define M2 16
#define NZR 32  // 16 low ky + 16 high ky modes

static __device__ __forceinline__ float2 ld2(const float* p) {
  return *reinterpret_cast<const float2*>(p);
}

constexpr float TWO_PI_OVER_256 = 6.28318530717958647692f / 256.0f;

// ---------------- K1: forward partial DFT per (b, in_ch) image ----------------
// Z[img][zr][kx][2], zr 0..15 -> ky=zr ; zr 16..31 -> ky=240+(zr-16)
__global__ __launch_bounds__(256) void k_fwd(const float* __restrict__ x,
                                             float* __restrict__ Z) {
  __shared__ float tw[256][2];   // cos, sin of 2*pi*j/256
  __shared__ float xs[32][260];  // 32-row chunk of the image, padded
  __shared__ float ys[256][34];  // y[h][2*kx+{0,1}]  (re, im), padded
  const int t = threadIdx.x;
  const int img = blockIdx.x;  // b*CIN + i
  {
    float s, c;
    sincosf(TWO_PI_OVER_256 * (float)t, &s, &c);
    tw[t][0] = c;
    tw[t][1] = s;
  }
  const int kx = t & 15;
  const int r0 = t >> 4;  // 0..15
  const float* xp = x + (size_t)img * (HH * WW);

  for (int chunk = 0; chunk < 8; ++chunk) {
    __syncthreads();  // xs readers from previous chunk done; tw ready (chunk 0)
    const float4* src4 = (const float4*)(xp + chunk * 32 * WW);
#pragma unroll
    for (int it = 0; it < 8; ++it) {
      int v = t + it * 256;
      float4 d = src4[v];
      int row = v >> 6;
      int col = (v & 63) << 2;
      *(float4*)&xs[row][col] = d;
    }
    __syncthreads();
    // y[h][kx] = sum_w x[h][w] * e^{-2*pi*i*kx*w/256} for rows r0 and r0+16
    float y0r = 0.f, y0i = 0.f, y1r = 0.f, y1i = 0.f;
    int idx = 0;
#pragma unroll 4
    for (int w = 0; w < WW; ++w) {
      float2 cs_ = ld2(&tw[idx][0]);
      float a0 = xs[r0][w];
      float a1 = xs[r0 + 16][w];
      y0r = fmaf(a0, cs_.x, y0r);
      y0i = fmaf(a0, -cs_.y, y0i);
      y1r = fmaf(a1, cs_.x, y1r);
      y1i = fmaf(a1, -cs_.y, y1i);
      idx = (idx + kx) & 255;
    }
    const int h0 = chunk * 32 + r0;
    ys[h0][2 * kx] = y0r;
    ys[h0][2 * kx + 1] = y0i;
    ys[h0 + 16][2 * kx] = y1r;
    ys[h0 + 16][2 * kx + 1] = y1i;
  }
  __syncthreads();
  // z[zr][kx] = sum_h y[h][kx] * e^{-2*pi*i*ky*h/256}
  const int j = t >> 4;  // 0..15
  float* zout = Z + (size_t)img * (NZR * M2 * 2);
#pragma unroll
  for (int pass = 0; pass < 2; ++pass) {
    const int ky = (pass == 0) ? j : (240 + j);
    const int zr = (pass == 0) ? j : (16 + j);
    float zacc_r = 0.f, zacc_i = 0.f;
    int idx = 0;
#pragma unroll 4
    for (int h = 0; h < HH; ++h) {
      float2 cs_ = ld2(&tw[idx][0]);
      float2 yv = ld2(&ys[h][2 * kx]);
      // (yr + i*yi) * (c - i*s)
      zacc_r += yv.x * cs_.x + yv.y * cs_.y;
      zacc_i += yv.y * cs_.x - yv.x * cs_.y;
      idx = (idx + ky) & 255;
    }
    zout[(zr * M2 + kx) * 2 + 0] = zacc_r;
    zout[(zr * M2 + kx) * 2 + 1] = zacc_i;
  }
}

// ---------------- K2: per-mode channel mix O = sum_i Z * C ----------------
__global__ __launch_bounds__(256) void k_mix(const float* __restrict__ Z,
                                             const float* __restrict__ w1,
                                             const float* __restrict__ w2,
                                             float* __restrict__ O) {
  __shared__ float zs[BB][CIN][2];
  __shared__ float cs[CIN][COUT][2];
  const int t = threadIdx.x;
  const int zr = blockIdx.x >> 4;  // 0..31
  const int kx = blockIdx.x & 15;
  const int kyi = zr & 15;
  const float* wsrc = (zr < M1) ? w1 : w2;
#pragma unroll
  for (int p = t; p < BB * CIN; p += 256) {
    int b = p >> 5, i = p & 31;
    const float* src = Z + ((size_t)((b * CIN + i) * NZR + zr) * M2 + kx) * 2;
    zs[b][i][0] = src[0];
    zs[b][i][1] = src[1];
  }
#pragma unroll
  for (int p = t; p < CIN * COUT; p += 256) {
    int i = p >> 5, oc = p & 31;
    const float* src =
        wsrc + ((size_t)((i * COUT + oc) * M1 + kyi) * M2 + kx) * 2;
    cs[i][oc][0] = src[0];
    cs[i][oc][1] = src[1];
  }
  __syncthreads();
  const int oc = t & 31;
  const int b0 = t >> 5;  // 0..7
#pragma unroll
  for (int pass = 0; pass < 2; ++pass) {
    const int b = b0 + pass * 8;
    float acc_r = 0.f, acc_i = 0.f;
#pragma unroll
    for (int i = 0; i < CIN; ++i) {
      float zrv = zs[b][i][0], ziv = zs[b][i][1];
      float cr = cs[i][oc][0], ci = cs[i][oc][1];
      acc_r += zrv * cr - ziv * ci;
      acc_i += zrv * ci + ziv * cr;
    }
    float* dst = O + ((size_t)((b * COUT + oc) * NZR + zr) * M2 + kx) * 2;
    dst[0] = acc_r;
    dst[1] = acc_i;
  }
}

// ---------------- K3: inverse transform per (b, out_ch) image ----------------
__global__ __launch_bounds__(256) void k_inv(const float* __restrict__ O,
                                             float* __restrict__ out) {
  __shared__ float tw[256][2];
  __shared__ float os[NZR][M2][2];  // 4 KB
  __shared__ float ts[256][34];     // T[h][2*kx+{0,1}], scaled
  const int t = threadIdx.x;
  const int img = blockIdx.x;  // b*COUT + oc
  {
    float s, c;
    sincosf(TWO_PI_OVER_256 * (float)t, &s, &c);
    tw[t][0] = c;
    tw[t][1] = s;
  }
  {
    const float4* src = (const float4*)(O + (size_t)img * (NZR * M2 * 2));
    float4 d = src[t];
    float* osf = &os[0][0][0];
    *(float4*)&osf[t * 4] = d;
  }
  __syncthreads();
  // Stage A: T[h][kx] = (scale) * sum_zr o[zr][kx] * e^{+2*pi*i*ky(zr)*h/256}
  const int kx = t & 15;
  const int h0 = t >> 4;  // 0..15
  const float scale = ((kx == 0) ? 1.0f : 2.0f) / 65536.0f;
#pragma unroll
  for (int m = 0; m < 16; ++m) {
    const int h = (m << 4) + h0;
    float tr = 0.f, ti = 0.f;
    int idx = 0;  // ky=0 start
#pragma unroll
    for (int zr = 0; zr < 16; ++zr) {
      float2 cs_ = ld2(&tw[idx][0]);
      float2 ov = ld2(&os[zr][kx][0]);
      tr += ov.x * cs_.x - ov.y * cs_.y;
      ti += ov.x * cs_.y + ov.y * cs_.x;
      idx = (idx + h) & 255;
    }
    idx = (240 * h) & 255;  // ky = 240 start
#pragma unroll
    for (int zr = 16; zr < 32; ++zr) {
      float2 cs_ = ld2(&tw[idx][0]);
      float2 ov = ld2(&os[zr][kx][0]);
      tr += ov.x * cs_.x - ov.y * cs_.y;
      ti += ov.x * cs_.y + ov.y * cs_.x;
      idx = (idx + h) & 255;
    }
    ts[h][2 * kx] = tr * scale;
    ts[h][2 * kx + 1] = ti * scale;
  }
  __syncthreads();
  // Stage B: out[h][w] = sum_kx (tr*cos - ti*sin)(2*pi*kx*w/256); w = t
  float cw[16], sw[16];
#pragma unroll
  for (int k = 0; k < 16; ++k) {
    int idx = (k * t) & 255;
    float2 cs_ = ld2(&tw[idx][0]);
    cw[k] = cs_.x;
    sw[k] = cs_.y;
  }
  float* op = out + (size_t)img * (HH * WW) + t;
  for (int h = 0; h < HH; ++h) {
    float acc = 0.f;
#pragma unroll
    for (int k = 0; k < 16; ++k) {
      float2 tv = ld2(&ts[h][2 * k]);
      acc += tv.x * cw[k] - tv.y * sw[k];
    }
    op[(size_t)h * WW] = acc;
  }
}

extern "C" void kernel_launch(void* const* d_in, const int* in_sizes, int n_in,
                              void* d_out, int out_size, void* d_ws,
                              size_t ws_size, hipStream_t stream) {
  const float* x = (const float*)d_in[0];
  const float* w1 = (const float*)d_in[1];
  const float* w2 = (const float*)d_in[2];
  float* out = (float*)d_out;
  // Workspace: Z (512*32*16*2 floats = 2 MB) then O (2 MB). Needs ws >= 4 MB.
  float* Z = (float*)d_ws;
  float* O = Z + (size_t)(BB * CIN) * NZR * M2 * 2;

  k_fwd<<<dim3(BB * CIN), dim3(256), 0, stream>>>(x, Z);
  k_mix<<<dim3(NZR * M2), dim3(256), 0, stream>>>(Z, w1, w2, O);
  k_inv<<<dim3(BB * COUT), dim3(256), 0, stream>>>(O, out);
}

// Round 2
// 131.072 us; speedup vs baseline: 1.4244x; 1.4244x over previous
//
#include <hip/hip_runtime.h>
#include <math.h>

// SpectralConv2d via partial separable DFT (only 32x16 modes of rfft2 used).
// B=16, CIN=COUT=32, H=W=256, M1=M2=16.
#define BB 16
#define CIN 32
#define COUT 32
#define HH 256
#define WW 256
#define M1 16
#define M2 16
#define NZR 32  // 16 low ky + 16 high ky modes

constexpr float TWO_PI_OVER_256 = 6.28318530717958647692f / 256.0f;

// Swizzled twiddle table: (cos,sin)(2*pi*i/256) stored at float2 slot i+(i>>4).
// For a gather idx=(k*w)&255 across 16 lanes, bank-pairs (idx+(idx>>4))&15 are
// distinct (or duplicate addresses -> broadcast) for every stride -> conflict-free.
#define TW_SLOTS 272
static __device__ __forceinline__ int twslot(int i) { return i + (i >> 4); }

// ---------------- K1: forward partial DFT per (img, h-half) ----------------
// Zp[img][half][zr][kx] float2 ; zr 0..15 -> ky=zr ; 16..31 -> ky=240+(zr-16)
__global__ __launch_bounds__(256) void k_fwd(const float* __restrict__ x,
                                             float* __restrict__ Zp) {
  __shared__ __align__(16) float2 twb[TW_SLOTS];
  __shared__ __align__(16) float xe[32][132];  // x[w] + x[w+128]
  __shared__ __align__(16) float xo[32][132];  // x[w] - x[w+128]
  __shared__ __align__(16) float ys[32][34];   // y[h][kx] (re,im)
  const int t = threadIdx.x;
  const int img = blockIdx.x >> 1;
  const int half = blockIdx.x & 1;
  {
    float s, c;
    sincosf(TWO_PI_OVER_256 * (float)t, &s, &c);
    twb[twslot(t)] = make_float2(c, s);
  }
  const int kx = t & 15;
  const int j = t >> 4;  // row index in row-phase; zr index in col-phase
  const float* rowsel = (kx & 1) ? &xo[0][0] : &xe[0][0];
  // column-DFT accumulators (ky = j and ky = 240+j), h starts at half*128
  float z0r = 0.f, z0i = 0.f, z1r = 0.f, z1i = 0.f;
  int idx0 = (j * half * 128) & 255;
  int idx1 = ((j + 240) * half * 128) & 255;
  const float* xp = x + (size_t)img * (HH * WW) + half * 128 * WW;

  for (int chunk = 0; chunk < 4; ++chunk) {
    // stage 32 rows with even/odd (w vs w+128) folding
    {
      const float* gp = xp + chunk * 32 * WW;
#pragma unroll
      for (int it = 0; it < 4; ++it) {
        int v = t + it * 256;
        int row = v >> 5, wq = (v & 31) << 2;
        float4 a = *(const float4*)(gp + row * WW + wq);
        float4 b = *(const float4*)(gp + row * WW + wq + 128);
        *(float4*)&xe[row][wq] =
            make_float4(a.x + b.x, a.y + b.y, a.z + b.z, a.w + b.w);
        *(float4*)&xo[row][wq] =
            make_float4(a.x - b.x, a.y - b.y, a.z - b.z, a.w - b.w);
      }
    }
    __syncthreads();
    // row DFT: rows j and j+16, freq kx, 128 taps (parity-folded)
    {
      const float* rA = rowsel + j * 132;
      const float* rB = rowsel + (j + 16) * 132;
      float y0r = 0.f, y0i = 0.f, y1r = 0.f, y1i = 0.f;
      int idx = 0;
#pragma unroll 4
      for (int w = 0; w < 128; ++w) {
        float2 cs = twb[twslot(idx)];
        float a0 = rA[w], a1 = rB[w];
        y0r = fmaf(a0, cs.x, y0r);
        y0i = fmaf(a0, -cs.y, y0i);
        y1r = fmaf(a1, cs.x, y1r);
        y1i = fmaf(a1, -cs.y, y1i);
        idx = (idx + kx) & 255;
      }
      *(float2*)&ys[j][2 * kx] = make_float2(y0r, y0i);
      *(float2*)&ys[j + 16][2 * kx] = make_float2(y1r, y1i);
    }
    __syncthreads();
    // column accumulate over these 32 h rows
#pragma unroll 4
    for (int hh = 0; hh < 32; ++hh) {
      float2 yv = *(const float2*)&ys[hh][2 * kx];
      float2 c0 = twb[twslot(idx0)];
      float2 c1 = twb[twslot(idx1)];
      z0r += yv.x * c0.x + yv.y * c0.y;
      z0i += yv.y * c0.x - yv.x * c0.y;
      z1r += yv.x * c1.x + yv.y * c1.y;
      z1i += yv.y * c1.x - yv.x * c1.y;
      idx0 = (idx0 + j) & 255;
      idx1 = (idx1 + j + 240) & 255;
    }
    // next chunk's staging may start while laggards finish col phase: staging
    // writes xe/xo which col phase doesn't read; the next barrier (top of row
    // phase) protects ys and xe/xo reuse.
  }
  float2* zout = (float2*)Zp + ((size_t)img * 2 + half) * (NZR * M2);
  zout[j * 16 + kx] = make_float2(z0r, z0i);
  zout[(16 + j) * 16 + kx] = make_float2(z1r, z1i);
}

// ---------------- K2: per-mode channel mix O = sum_i (Zp0+Zp1) * C ----------
__global__ __launch_bounds__(256) void k_mix(const float* __restrict__ Zp,
                                             const float* __restrict__ w1,
                                             const float* __restrict__ w2,
                                             float* __restrict__ O) {
  __shared__ float2 zs[BB][CIN];
  __shared__ float2 cs[CIN][COUT];
  const int t = threadIdx.x;
  const int zr = blockIdx.x >> 4;  // 0..31
  const int kx = blockIdx.x & 15;
  const int kyi = zr & 15;
  const float* wsrc = (zr < M1) ? w1 : w2;
  const float2* Z2 = (const float2*)Zp;
#pragma unroll
  for (int p = t; p < BB * CIN; p += 256) {
    int b = p >> 5, i = p & 31;
    size_t img = (size_t)(b * CIN + i);
    float2 a = Z2[(img * 2 + 0) * (NZR * M2) + zr * M2 + kx];
    float2 c = Z2[(img * 2 + 1) * (NZR * M2) + zr * M2 + kx];
    zs[b][i] = make_float2(a.x + c.x, a.y + c.y);
  }
#pragma unroll
  for (int p = t; p < CIN * COUT; p += 256) {
    int i = p >> 5, oc = p & 31;
    const float* src =
        wsrc + ((size_t)((i * COUT + oc) * M1 + kyi) * M2 + kx) * 2;
    cs[i][oc] = make_float2(src[0], src[1]);
  }
  __syncthreads();
  const int oc = t & 31;
  const int b0 = t >> 5;  // 0..7
#pragma unroll
  for (int pass = 0; pass < 2; ++pass) {
    const int b = b0 + pass * 8;
    float acc_r = 0.f, acc_i = 0.f;
#pragma unroll
    for (int i = 0; i < CIN; ++i) {
      float2 zv = zs[b][i];
      float2 cv = cs[i][oc];
      acc_r += zv.x * cv.x - zv.y * cv.y;
      acc_i += zv.x * cv.y + zv.y * cv.x;
    }
    float2* dst =
        (float2*)O + (size_t)((b * COUT + oc) * NZR + zr) * M2 + kx;
    *dst = make_float2(acc_r, acc_i);
  }
}

// ---------------- K3: inverse transform per (img, 64-row chunk) -------------
__global__ __launch_bounds__(256) void k_inv(const float* __restrict__ O,
                                             float* __restrict__ out) {
  __shared__ __align__(16) float2 twb[TW_SLOTS];
  __shared__ __align__(16) float2 osv[NZR * M2];
  __shared__ __align__(16) float ts[64][34];
  const int t = threadIdx.x;
  const int img = blockIdx.x >> 2;
  const int hc = blockIdx.x & 3;
  {
    float s, c;
    sincosf(TWO_PI_OVER_256 * (float)t, &s, &c);
    twb[twslot(t)] = make_float2(c, s);
  }
  {
    float4 d = ((const float4*)(O + (size_t)img * (NZR * M2 * 2)))[t];
    *(float4*)&osv[2 * t] = d;
  }
  __syncthreads();
  // Stage A: ts[hl][kx] = scale * sum_zr o[zr][kx] * e^{+2*pi*i*ky*h/256}
  const int kx = t & 15;
  const int h0 = t >> 4;  // 0..15
  const float scale = ((kx == 0) ? 1.0f : 2.0f) / 65536.0f;
#pragma unroll
  for (int m = 0; m < 4; ++m) {
    const int hl = m * 16 + h0;
    const int h = hc * 64 + hl;
    float tr = 0.f, ti = 0.f;
    int idx = 0;
#pragma unroll 4
    for (int zr = 0; zr < 16; ++zr) {
      float2 cs = twb[twslot(idx)];
      float2 ov = osv[zr * 16 + kx];
      tr += ov.x * cs.x - ov.y * cs.y;
      ti += ov.x * cs.y + ov.y * cs.x;
      idx = (idx + h) & 255;
    }
    idx = (240 * h) & 255;
#pragma unroll 4
    for (int zr = 16; zr < 32; ++zr) {
      float2 cs = twb[twslot(idx)];
      float2 ov = osv[zr * 16 + kx];
      tr += ov.x * cs.x - ov.y * cs.y;
      ti += ov.x * cs.y + ov.y * cs.x;
      idx = (idx + h) & 255;
    }
    *(float2*)&ts[hl][2 * kx] = make_float2(tr * scale, ti * scale);
  }
  // Stage B: out[h][w'] = E+O, out[h][w'+128] = E-O  (even/odd kx split)
  const int wp = t & 127;
  float cw[16], sw[16];
#pragma unroll
  for (int k = 0; k < 16; ++k) {
    int idx = (k * wp) & 255;
    float2 c = twb[twslot(idx)];
    cw[k] = c.x;
    sw[k] = c.y;
  }
  __syncthreads();
  const int hpar = t >> 7;  // 0 or 1
  float* op = out + (size_t)img * (HH * WW);
#pragma unroll 2
  for (int i = 0; i < 32; ++i) {
    const int hl = i * 2 + hpar;
    float E = 0.f, Od = 0.f;
#pragma unroll
    for (int k = 0; k < 16; k += 2) {
      float2 te = *(const float2*)&ts[hl][2 * k];
      float2 to = *(const float2*)&ts[hl][2 * k + 2];
      E += te.x * cw[k] - te.y * sw[k];
      Od += to.x * cw[k + 1] - to.y * sw[k + 1];
    }
    const int h = hc * 64 + hl;
    op[(size_t)h * WW + wp] = E + Od;
    op[(size_t)h * WW + wp + 128] = E - Od;
  }
}

extern "C" void kernel_launch(void* const* d_in, const int* in_sizes, int n_in,
                              void* d_out, int out_size, void* d_ws,
                              size_t ws_size, hipStream_t stream) {
  const float* x = (const float*)d_in[0];
  const float* w1 = (const float*)d_in[1];
  const float* w2 = (const float*)d_in[2];
  float* out = (float*)d_out;
  // Workspace: Zp (512 img * 2 halves * 512 float2 = 4 MB) then O (2 MB).
  float* Zp = (float*)d_ws;
  float* O = Zp + (size_t)(BB * CIN) * 2 * NZR * M2 * 2;

  k_fwd<<<dim3(BB * CIN * 2), dim3(256), 0, stream>>>(x, Zp);
  k_mix<<<dim3(NZR * M2), dim3(256), 0, stream>>>(Zp, w1, w2, O);
  k_inv<<<dim3(BB * COUT * 4), dim3(256), 0, stream>>>(O, out);
}

// Round 3
// 81.448 us; speedup vs baseline: 2.2922x; 1.6093x over previous
//
#include <hip/hip_runtime.h>
#include <math.h>

// SpectralConv2d: all DFT stages as fp16 split-precision MFMA GEMMs.
// B=16, CIN=COUT=32, H=W=256, modes 16x16 (32 ky rows x 16 kx).
#define BB 16
#define CC 32
#define HH 256
#define WW 256
#define NIMG (BB * CC)  // 512

typedef _Float16 f16;
typedef __attribute__((ext_vector_type(8))) _Float16 f16x8;
typedef __attribute__((ext_vector_type(4))) float f32x4;

constexpr float TWO_PI_OVER_256 = 6.28318530717958647692f / 256.0f;

// ws layout (f16 element counts for the fragment tables):
//  TwF  (fwd-row  B frags) [nt2][ks8][lane64][j8]   = 8192   per plane
//  AcolF(fwd-col  A frags) [mt4][ks16][lane64][j8]  = 32768
//  AinvF(inv-col  A frags) [mt16][ks2][lane64][j8]  = 16384
//  BinvF(inv-row  B frags) [nt16][lane64][j8]       = 8192
#define N_TWF 8192
#define N_ACOL 32768
#define N_AINV 16384
#define N_BINV 8192

static __device__ __forceinline__ f32x4 mfma3(f16x8 ah, f16x8 al, f16x8 bh,
                                              f16x8 bl, f32x4 c) {
  c = __builtin_amdgcn_mfma_f32_16x16x32_f16(ah, bh, c, 0, 0, 0);
  c = __builtin_amdgcn_mfma_f32_16x16x32_f16(ah, bl, c, 0, 0, 0);
  c = __builtin_amdgcn_mfma_f32_16x16x32_f16(al, bh, c, 0, 0, 0);
  return c;
}

static __device__ __forceinline__ void split16(float v, f16* hi, f16* lo) {
  f16 h_ = (f16)v;
  *hi = h_;
  *lo = (f16)(v - (float)h_);
}

// ---------------- k_tw: build twiddle fragment tables ----------------
__global__ __launch_bounds__(256) void k_tw(f16* __restrict__ fb) {
  const int id = blockIdx.x * 256 + threadIdx.x;  // 0..65535
  f16* twf_hi = fb;
  f16* twf_lo = twf_hi + N_TWF;
  f16* acol_hi = twf_lo + N_TWF;
  f16* acol_lo = acol_hi + N_ACOL;
  f16* ainv_hi = acol_lo + N_ACOL;
  f16* ainv_lo = ainv_hi + N_AINV;
  f16* binv_hi = ainv_lo + N_AINV;
  f16* binv_lo = binv_hi + N_BINV;

  float v;
  f16 *dh, *dl;
  if (id < N_TWF) {
    // fwd-row B[w][n]: n=2kx+ri: ri==0 -> cos(2pi kx w/256), ri==1 -> -sin
    int idx = id;
    int j = idx & 7, lane = (idx >> 3) & 63, ks = (idx >> 9) & 7,
        nt = (idx >> 12) & 1;
    int col = nt * 16 + (lane & 15);
    int w = ks * 32 + ((lane >> 4) << 3) + j;
    int kx = col >> 1, ri = col & 1;
    int ph = (kx * w) & 255;
    float s, c;
    sincosf(TWO_PI_OVER_256 * (float)ph, &s, &c);
    v = ri ? -s : c;
    dh = twf_hi + idx;
    dl = twf_lo + idx;
  } else if (id < N_TWF + N_ACOL) {
    // fwd-col A[row][k]: rows 0..31 = Zr(zr), 32..63 = Zi; k=2h+rj
    // Zr: (c, s) ; Zi: (-s, c)  with angle 2pi*ky*h/256 (fwd: e^{-i})
    int idx = id - N_TWF;
    int j = idx & 7, lane = (idx >> 3) & 63, ks = (idx >> 9) & 15,
        mt = (idx >> 13) & 3;
    int row = mt * 16 + (lane & 15);
    int k = ks * 32 + ((lane >> 4) << 3) + j;
    int h = k >> 1, rj = k & 1;
    int zr = (row < 32) ? row : row - 32;
    int ky = (zr < 16) ? zr : 224 + zr;
    int ph = (ky * h) & 255;
    float s, c;
    sincosf(TWO_PI_OVER_256 * (float)ph, &s, &c);
    if (row < 32)
      v = rj ? s : c;
    else
      v = rj ? c : -s;
    dh = acol_hi + idx;
    dl = acol_lo + idx;
  } else if (id < N_TWF + N_ACOL + N_AINV) {
    // inv-col A[h][k]: k=2zr+rj: (cos, sin) of +2pi*ky*h/256
    int idx = id - N_TWF - N_ACOL;
    int j = idx & 7, lane = (idx >> 3) & 63, ks = (idx >> 9) & 1,
        mt = (idx >> 10) & 15;
    int h = mt * 16 + (lane & 15);
    int k = ks * 32 + ((lane >> 4) << 3) + j;
    int zr = k >> 1, rj = k & 1;
    int ky = (zr < 16) ? zr : 224 + zr;
    int ph = (ky * h) & 255;
    float s, c;
    sincosf(TWO_PI_OVER_256 * (float)ph, &s, &c);
    v = rj ? s : c;
    dh = ainv_hi + idx;
    dl = ainv_lo + idx;
  } else {
    // inv-row B[k][w]: k=2kx+ri: ri==0 -> scale*cos(2pi kx w/256), ri==1 ->
    // -scale*sin ; scale = (kx?2:1)/65536
    int idx = id - N_TWF - N_ACOL - N_AINV;
    int j = idx & 7, lane = (idx >> 3) & 63, nt = (idx >> 9) & 15;
    int w = nt * 16 + (lane & 15);
    int k = ((lane >> 4) << 3) + j;
    int kx = k >> 1, ri = k & 1;
    int ph = (kx * w) & 255;
    float s, c;
    sincosf(TWO_PI_OVER_256 * (float)ph, &s, &c);
    float scale = ((kx == 0) ? 1.0f : 2.0f) / 65536.0f;
    v = ri ? -scale * s : scale * c;
    dh = binv_hi + idx;
    dl = binv_lo + idx;
  }
  f16 hi, lo;
  split16(v, &hi, &lo);
  *dh = hi;
  *dl = lo;
}

// ---------------- k_fwd: per-image forward (row GEMM + col GEMM) ------------
// Z[img][row64][kx16] f32 : rows 0..31 = Zr(zr), rows 32..63 = Zi(zr)
__global__ __launch_bounds__(256) void k_fwd(const float* __restrict__ x,
                                             const f16* __restrict__ twf_hi,
                                             const f16* __restrict__ twf_lo,
                                             const f16* __restrict__ acol_hi,
                                             const f16* __restrict__ acol_lo,
                                             float* __restrict__ Z) {
  __shared__ __align__(16) f16 Yc_hi[16 * 520];  // [kx][k=2h+ri], pad 520
  __shared__ __align__(16) f16 Yc_lo[16 * 520];
  const int t = threadIdx.x, lane = t & 63, wid = t >> 6;
  const int l15 = lane & 15, kgrp = lane >> 4;
  const int img = blockIdx.x;
  const float* xim = x + (size_t)img * (HH * WW);

  // row phase: Y = X[256x256] * TwF[256x32], 4 rounds x (1 mtile/wave)
  for (int r = 0; r < 4; ++r) {
    const int mt = r * 4 + wid;
    f32x4 acc0 = {0.f, 0.f, 0.f, 0.f}, acc1 = {0.f, 0.f, 0.f, 0.f};
    const float* ap = xim + (mt * 16 + l15) * WW + kgrp * 8;
#pragma unroll
    for (int ks = 0; ks < 8; ++ks) {
      float4 v0 = *(const float4*)(ap + ks * 32);
      float4 v1 = *(const float4*)(ap + ks * 32 + 4);
      float vv[8] = {v0.x, v0.y, v0.z, v0.w, v1.x, v1.y, v1.z, v1.w};
      f16x8 ah, al;
#pragma unroll
      for (int e = 0; e < 8; ++e) {
        f16 h_ = (f16)vv[e];
        ah[e] = h_;
        al[e] = (f16)(vv[e] - (float)h_);
      }
      const int b0 = ((0 * 8 + ks) * 64 + lane) * 8;
      const int b1 = ((1 * 8 + ks) * 64 + lane) * 8;
      f16x8 b0h = *(const f16x8*)(twf_hi + b0);
      f16x8 b0l = *(const f16x8*)(twf_lo + b0);
      f16x8 b1h = *(const f16x8*)(twf_hi + b1);
      f16x8 b1l = *(const f16x8*)(twf_lo + b1);
      acc0 = mfma3(ah, al, b0h, b0l, acc0);
      acc1 = mfma3(ah, al, b1h, b1l, acc1);
    }
    // scatter Y tile -> Yc (f16 hi/lo), B-layout for col GEMM: Yc[kx][2h+ri]
#pragma unroll
    for (int nt = 0; nt < 2; ++nt) {
#pragma unroll
      for (int jj = 0; jj < 4; ++jj) {
        const int h = mt * 16 + kgrp * 4 + jj;
        const int n = nt * 16 + l15;
        const int kx = n >> 1, ri = n & 1;
        float v = (nt == 0) ? acc0[jj] : acc1[jj];
        f16 hv = (f16)v;
        Yc_hi[kx * 520 + 2 * h + ri] = hv;
        Yc_lo[kx * 520 + 2 * h + ri] = (f16)(v - (float)hv);
      }
    }
  }
  __syncthreads();
  // col phase: [Zr|Zi](64 x 16) = AcolF(64 x 512) * Yc(512 x 16)
  f32x4 zacc = {0.f, 0.f, 0.f, 0.f};
#pragma unroll 4
  for (int ks = 0; ks < 16; ++ks) {
    const int ao = ((wid * 16 + ks) * 64 + lane) * 8;
    f16x8 a_h = *(const f16x8*)(acol_hi + ao);
    f16x8 a_l = *(const f16x8*)(acol_lo + ao);
    const int bo = l15 * 520 + ks * 32 + kgrp * 8;
    f16x8 b_h = *(const f16x8*)(Yc_hi + bo);
    f16x8 b_l = *(const f16x8*)(Yc_lo + bo);
    zacc = mfma3(a_h, a_l, b_h, b_l, zacc);
  }
  float* zp = Z + (size_t)img * 1024;
#pragma unroll
  for (int jj = 0; jj < 4; ++jj) {
    const int row = wid * 16 + kgrp * 4 + jj;
    zp[row * 16 + l15] = zacc[jj];
  }
}

// ---------------- k_mix: per-mode channel mix (VALU) ----------------
// O[(b*32+oc)][zr*16+kx] float2
__global__ __launch_bounds__(256) void k_mix(const float* __restrict__ Z,
                                             const float* __restrict__ w1,
                                             const float* __restrict__ w2,
                                             float* __restrict__ O) {
  __shared__ float2 zs[BB][CC];
  __shared__ float2 cs[CC][CC];
  const int t = threadIdx.x;
  const int zr = blockIdx.x >> 4;  // 0..31
  const int kx = blockIdx.x & 15;
  const int kyi = zr & 15;
  const float* wsrc = (zr < 16) ? w1 : w2;
#pragma unroll
  for (int p = t; p < BB * CC; p += 256) {
    int b = p >> 5, i = p & 31;
    const float* zi = Z + (size_t)(b * CC + i) * 1024;
    zs[b][i] = make_float2(zi[zr * 16 + kx], zi[512 + zr * 16 + kx]);
  }
#pragma unroll
  for (int p = t; p < CC * CC; p += 256) {
    int i = p >> 5, oc = p & 31;
    const float* src = wsrc + ((size_t)((i * CC + oc) * 16 + kyi) * 16 + kx) * 2;
    cs[i][oc] = make_float2(src[0], src[1]);
  }
  __syncthreads();
  const int oc = t & 31;
  const int b0 = t >> 5;  // 0..7
#pragma unroll
  for (int pass = 0; pass < 2; ++pass) {
    const int b = b0 + pass * 8;
    float acc_r = 0.f, acc_i = 0.f;
#pragma unroll
    for (int i = 0; i < CC; ++i) {
      float2 zv = zs[b][i];
      float2 cv = cs[i][oc];
      acc_r += zv.x * cv.x - zv.y * cv.y;
      acc_i += zv.x * cv.y + zv.y * cv.x;
    }
    float2* dst = (float2*)O + (size_t)(b * CC + oc) * 512 + zr * 16 + kx;
    *dst = make_float2(acc_r, acc_i);
  }
}

// ---------------- k_inv: per-image inverse (col GEMM + row GEMM) ------------
__global__ __launch_bounds__(256) void k_inv(const float* __restrict__ O,
                                             const f16* __restrict__ ainv_hi,
                                             const f16* __restrict__ ainv_lo,
                                             const f16* __restrict__ binv_hi,
                                             const f16* __restrict__ binv_lo,
                                             float* __restrict__ out) {
  __shared__ float Olds[1024];
  __shared__ __align__(16) f16 Bf_hi[2048], Bf_lo[2048];
  __shared__ __align__(16) f16 T_hi[256 * 40], T_lo[256 * 40];
  const int t = threadIdx.x, lane = t & 63, wid = t >> 6;
  const int l15 = lane & 15, kgrp = lane >> 4;
  const int img = blockIdx.x;
  {
    float4 v = ((const float4*)(O + (size_t)img * 1024))[t];
    *(float4*)&Olds[t * 4] = v;
  }
  __syncthreads();
  // build B frags for col GEMM: B[k=2zr+rj][n=2kx+ri] from O
#pragma unroll
  for (int e = 0; e < 8; ++e) {
    const int idx = e * 256 + t;  // 0..2047 = ((nt*2+ks)*64+lane)*8+j
    const int nt = idx >> 10, ks = (idx >> 9) & 1, ln = (idx >> 3) & 63,
              j = idx & 7;
    const int k = ks * 32 + ((ln >> 4) << 3) + j;
    const int n = nt * 16 + (ln & 15);
    const int zr = k >> 1, rj = k & 1, kx = n >> 1, ri = n & 1;
    const float Or = Olds[(zr * 16 + kx) * 2];
    const float Oi = Olds[(zr * 16 + kx) * 2 + 1];
    const float v = (rj == 0) ? (ri == 0 ? Or : Oi) : (ri == 0 ? -Oi : Or);
    f16 hv = (f16)v;
    Bf_hi[idx] = hv;
    Bf_lo[idx] = (f16)(v - (float)hv);
  }
  __syncthreads();
  // col GEMM: T(256 x 32) = AinvF(256 x 64) * Bf(64 x 32); store as f16 hi/lo
#pragma unroll
  for (int mm = 0; mm < 4; ++mm) {
    const int mt = wid * 4 + mm;
    f32x4 acc0 = {0.f, 0.f, 0.f, 0.f}, acc1 = {0.f, 0.f, 0.f, 0.f};
#pragma unroll
    for (int ks = 0; ks < 2; ++ks) {
      const int ao = ((mt * 2 + ks) * 64 + lane) * 8;
      f16x8 a_h = *(const f16x8*)(ainv_hi + ao);
      f16x8 a_l = *(const f16x8*)(ainv_lo + ao);
      const int bo0 = ((0 * 2 + ks) * 64 + lane) * 8;
      const int bo1 = ((1 * 2 + ks) * 64 + lane) * 8;
      f16x8 b0h = *(const f16x8*)(Bf_hi + bo0);
      f16x8 b0l = *(const f16x8*)(Bf_lo + bo0);
      f16x8 b1h = *(const f16x8*)(Bf_hi + bo1);
      f16x8 b1l = *(const f16x8*)(Bf_lo + bo1);
      acc0 = mfma3(a_h, a_l, b0h, b0l, acc0);
      acc1 = mfma3(a_h, a_l, b1h, b1l, acc1);
    }
#pragma unroll
    for (int nt = 0; nt < 2; ++nt) {
#pragma unroll
      for (int jj = 0; jj < 4; ++jj) {
        const int h = mt * 16 + kgrp * 4 + jj;
        const int n = nt * 16 + l15;
        float v = (nt == 0) ? acc0[jj] : acc1[jj];
        f16 hv = (f16)v;
        T_hi[h * 40 + n] = hv;
        T_lo[h * 40 + n] = (f16)(v - (float)hv);
      }
    }
  }
  __syncthreads();
  // row GEMM: out(256 x 256) = T(256 x 32) * BinvF(32 x 256)
  float* op = out + (size_t)img * (HH * WW);
#pragma unroll
  for (int mm = 0; mm < 4; ++mm) {
    const int mt = wid * 4 + mm;
    const int ao = (mt * 16 + l15) * 40 + kgrp * 8;
    f16x8 a_h = *(const f16x8*)(T_hi + ao);
    f16x8 a_l = *(const f16x8*)(T_lo + ao);
#pragma unroll 4
    for (int nt = 0; nt < 16; ++nt) {
      const int bo = (nt * 64 + lane) * 8;
      f16x8 b_h = *(const f16x8*)(binv_hi + bo);
      f16x8 b_l = *(const f16x8*)(binv_lo + bo);
      f32x4 acc = {0.f, 0.f, 0.f, 0.f};
      acc = mfma3(a_h, a_l, b_h, b_l, acc);
#pragma unroll
      for (int jj = 0; jj < 4; ++jj) {
        const int h = mt * 16 + kgrp * 4 + jj;
        op[(size_t)h * WW + nt * 16 + l15] = acc[jj];
      }
    }
  }
}

extern "C" void kernel_launch(void* const* d_in, const int* in_sizes, int n_in,
                              void* d_out, int out_size, void* d_ws,
                              size_t ws_size, hipStream_t stream) {
  const float* x = (const float*)d_in[0];
  const float* w1 = (const float*)d_in[1];
  const float* w2 = (const float*)d_in[2];
  float* out = (float*)d_out;

  f16* fb = (f16*)d_ws;
  f16* twf_hi = fb;
  f16* twf_lo = twf_hi + N_TWF;
  f16* acol_hi = twf_lo + N_TWF;
  f16* acol_lo = acol_hi + N_ACOL;
  f16* ainv_hi = acol_lo + N_ACOL;
  f16* ainv_lo = ainv_hi + N_AINV;
  f16* binv_hi = ainv_lo + N_AINV;
  f16* binv_lo = binv_hi + N_BINV;
  float* Z = (float*)(binv_lo + N_BINV);  // 512*1024 f32 = 2 MB
  float* O = Z + (size_t)NIMG * 1024;     // 512*1024 f32 = 2 MB

  k_tw<<<dim3(256), dim3(256), 0, stream>>>(fb);
  k_fwd<<<dim3(NIMG), dim3(256), 0, stream>>>(x, twf_hi, twf_lo, acol_hi,
                                              acol_lo, Z);
  k_mix<<<dim3(512), dim3(256), 0, stream>>>(Z, w1, w2, O);
  k_inv<<<dim3(NIMG), dim3(256), 0, stream>>>(O, ainv_hi, ainv_lo, binv_hi,
                                              binv_lo, out);
}